// Round 8
// baseline (389.682 us; speedup 1.0000x reference)
//
#include <hip/hip_runtime.h>
#include <hip/hip_bf16.h>

// ============================================================================
// HRR "self-attention" on MI355X (gfx950).
//
// out = irfft( cumsum_S( (Fk/(|Fk|+eps)) * Fv ) * conj(Fq/(|Fq|+eps)) )
// q,k,v = x @ W^T via Ozaki 3-product bf16 split GEMM (f32-grade).
//
// This round: GEMM ported to the 256^2 8-phase counted-vmcnt template
// (T2 swizzle + T3/T4 counted vmcnt + T5 setprio). 4 phases per K-tile
// (BK=64), double-buffered LDS, raw s_barrier (no vmcnt-draining
// __syncthreads in the K-loop), one s_waitcnt vmcnt(2) per K-tile.
//
// Workspace (142 MiB peak, aliased):
//   [0,32M)    xhi|xlo  (dead after GEMM)  === fkv (first written in fwd_fft)
//   [33M,+6KB) gtw (twiddle table)
//   [34,46M)   whi|wlo  (dead after GEMM)
//   [46,142M)  qkv f32  (rows also carry Fqh in-place after fwd_fft)
// ============================================================================

using bf16 = __hip_bfloat16;

typedef __attribute__((ext_vector_type(8))) short bf16x8;
typedef __attribute__((ext_vector_type(4))) float f32x4;

#define DEV static __device__ __forceinline__

#define BB 4
#define SS 2048
#define DD 1024
#define BS (BB * SS)   // 8192 rows
#define NBIN 513
#define N3 3072
#define KTILES 48      // 3072 / 64

// Padded FFT LDS index: bijective, strictly increasing, max 1086 (< 1088).
#define ZIDX(e) ((e) + ((e) >> 4))
#define ZLEN 1088

DEV float2 cmul(float2 a, float2 b) { return make_float2(a.x*b.x - a.y*b.y, a.x*b.y + a.y*b.x); }
DEV float2 cadd(float2 a, float2 b) { return make_float2(a.x + b.x, a.y + b.y); }
DEV float2 csub(float2 a, float2 b) { return make_float2(a.x - b.x, a.y - b.y); }
DEV float2 conjf2(float2 a) { return make_float2(a.x, -a.y); }

// Reverse the 5 base-4 digits of a 10-bit index (involution).
DEV int rev4(int n) {
  int r = 0;
#pragma unroll
  for (int d = 0; d < 5; ++d) { r = (r << 2) | (n & 3); n >>= 2; }
  return r;
}

DEV void bf16_split(float v, ushort &hi, ushort &lo) {
  bf16 hb = __float2bfloat16(v);
  float hf = __bfloat162float(hb);
  bf16 lb = __float2bfloat16(v - hf);
  hi = *reinterpret_cast<ushort*>(&hb);
  lo = *reinterpret_cast<ushort*>(&lb);
}

// ---------------------------------------------------------------------------
// gtw[i] = e^{-2pi*I*i/1024}, i in [0,768).
__global__ __launch_bounds__(256) void tw_init_k(float2* __restrict__ gtw) {
  const int i = blockIdx.x * 256 + threadIdx.x;      // grid=3 -> i in [0,768)
  float sv, cv;
  sincosf(-6.283185307179586f * (float)i * (1.0f / 1024.0f), &sv, &cv);
  gtw[i] = make_float2(cv, sv);
}

DEV void init_tw(float2* tw, const float2* __restrict__ gtw, const int tid) {
#pragma unroll
  for (int rep = 0; rep < 3; ++rep) {
    const int i = tid + rep * 256;
    tw[i] = gtw[i];
  }
}

// ---------------------------------------------------------------------------
__global__ __launch_bounds__(256) void prep_x_k(const float* __restrict__ x,
                                                bf16* __restrict__ xhi,
                                                bf16* __restrict__ xlo) {
  const int i = blockIdx.x * 256 + threadIdx.x;      // float4 index
  const float4 v = reinterpret_cast<const float4*>(x)[i];
  const float f[4] = {v.x, v.y, v.z, v.w};
  ushort h[4], l[4];
#pragma unroll
  for (int j = 0; j < 4; ++j) bf16_split(f[j], h[j], l[j]);
  reinterpret_cast<ushort4*>(xhi)[i] = make_ushort4(h[0], h[1], h[2], h[3]);
  reinterpret_cast<ushort4*>(xlo)[i] = make_ushort4(l[0], l[1], l[2], l[3]);
}

__global__ __launch_bounds__(256) void prep_w_k(const float* __restrict__ wq,
                                                const float* __restrict__ wk,
                                                const float* __restrict__ wv,
                                                bf16* __restrict__ whi,
                                                bf16* __restrict__ wlo) {
  const int i = blockIdx.x * 256 + threadIdx.x;      // float4 index
  const int e = i << 2;
  const int row = e >> 10;                           // 0..3071 over (Wq;Wk;Wv)
  const float* src = (row < 1024) ? wq : ((row < 2048) ? wk : wv);
  const float4 v = *reinterpret_cast<const float4*>(src + (size_t)(row & 1023) * 1024 + (e & 1023));
  const float f[4] = {v.x, v.y, v.z, v.w};
  ushort h[4], l[4];
#pragma unroll
  for (int j = 0; j < 4; ++j) bf16_split(f[j], h[j], l[j]);
  reinterpret_cast<ushort4*>(whi)[i] = make_ushort4(h[0], h[1], h[2], h[3]);
  reinterpret_cast<ushort4*>(wlo)[i] = make_ushort4(l[0], l[1], l[2], l[3]);
}

// ---------------------------------------------------------------------------
DEV void load_lds16(const bf16* g, bf16* l) {
  __builtin_amdgcn_global_load_lds((const __attribute__((address_space(1))) void*)g,
                                   (__attribute__((address_space(3))) void*)l, 16, 0, 0);
}

// ===========================================================================
// 8-phase 256x256xBK64 GEMM. C = A'.B'^T, M=8192, N=3072, K'=3072.
// 512 threads = 8 waves (2M x 4N); per-wave 128x64 output (8m x 4n frags).
// 4 phases per K-tile: (ks,mh) in {0,1}x{0,1}; 16 MFMA each.
// LDS: 2 dbuf x 2 half x [128][64] bf16 for A and B = 128 KiB.
// T2 swizzle: element col ^= (row&7)<<3 (byte ^= (row&7)<<4) -> 2-way banks.
//   Applied as: linear LDS dest (global_load_lds) + inverse-swizzled GLOBAL
//   source + swizzled ds_read address (both-sides, rule #21).
// T3/T4: raw s_barrier; one s_waitcnt vmcnt(2) per K-tile (phase 0) -- tile
//   t's 8 loads confirmed, the 2 newest (t+1 half-tile 0) stay in flight.
// T5: setprio(1) around each MFMA cluster.
// ===========================================================================
__global__ __launch_bounds__(512, 2) void gemm_8ph(const bf16* __restrict__ xhi,
                                                   const bf16* __restrict__ xlo,
                                                   const bf16* __restrict__ whi,
                                                   const bf16* __restrict__ wlo,
                                                   float* __restrict__ qkv) {
  __shared__ bf16 Ab[2][2][128 * 64];
  __shared__ bf16 Bb[2][2][128 * 64];
  const int tid = threadIdx.x;
  const int lane = tid & 63;
  const int w = tid >> 6;           // wave 0..7
  const int wm = w >> 2;            // 0..1 (M half)
  const int wn = w & 3;             // 0..3 (N quarter)
  // XCD-chunked swizzle: 384 blocks (384%8==0 -> bijective), 48/XCD.
  const int bid = blockIdx.x;
  const int logical = (bid & 7) * 48 + (bid >> 3);
  const int bn = logical % 12;
  const int bm = logical / 12;
  const int rowBase = bm * 256, colBase = bn * 256;

  // Staging geometry: line g of a half-tile covers rows g*64 + w*8 + lane/8,
  // 16B per lane. LDS dest linear (wave-uniform base + lane*16 by HW).
  // Global col pre-swizzled: scol = ((lane&7)*8) ^ ((row&7)<<3), row&7=lane>>3.
  const int srow = (w << 3) + (lane >> 3);                 // 0..63
  const int scol = ((lane & 7) << 3) ^ ((lane >> 3) << 3); // elements

  // MFMA fragment coords (16x16x32): lr = row-in-frag, lk = k-quarter.
  const int lr = lane & 15;
  const int lk = (lane >> 4) * 8;

  f32x4 acc[8][4];
#pragma unroll
  for (int m = 0; m < 8; ++m)
#pragma unroll
    for (int n = 0; n < 4; ++n) acc[m][n] = 0.0f;

  // ---- stage helpers: one half-tile = 2 global_load_lds lines ----
  auto stageA = [&](int kt, int d, int h) {
    const int part = (kt * 64) >> 10;                 // 0:hi 1:hi 2:lo
    const bf16* As = (part < 2) ? xhi : xlo;
    const int kb = (kt * 64) & 1023;
#pragma unroll
    for (int g = 0; g < 2; ++g)
      load_lds16(As + (size_t)(rowBase + h * 128 + g * 64 + srow) * 1024 + kb + scol,
                 &Ab[d][h][g * 4096 + w * 512]);
  };
  auto stageB = [&](int kt, int d, int h) {
    const int part = (kt * 64) >> 10;                 // 0:hi 1:lo 2:hi
    const bf16* Bs = (part == 1) ? wlo : whi;
    const int kb = (kt * 64) & 1023;
#pragma unroll
    for (int g = 0; g < 2; ++g)
      load_lds16(Bs + (size_t)(colBase + h * 128 + g * 64 + srow) * 1024 + kb + scol,
                 &Bb[d][h][g * 4096 + w * 512]);
  };

  // ---- frag readers (swizzled LDS address) ----
  auto readA = [&](bf16x8* af, int d, int ks, int mh) {
#pragma unroll
    for (int m = 0; m < 4; ++m) {
      const int r = (mh * 4 + m) * 16 + lr;           // 0..127 in half wm
      const int c = ks * 32 + lk;
      af[m] = *reinterpret_cast<const bf16x8*>(&Ab[d][wm][r * 64 + (c ^ ((r & 7) << 3))]);
    }
  };
  auto readB = [&](bf16x8* bfr, int d, int ks) {
#pragma unroll
    for (int n = 0; n < 4; ++n) {
      const int rB = (wn & 1) * 64 + n * 16 + lr;     // 0..127 in half wn>>1
      const int c = ks * 32 + lk;
      bfr[n] = *reinterpret_cast<const bf16x8*>(&Bb[d][wn >> 1][rB * 64 + (c ^ ((rB & 7) << 3))]);
    }
  };

  // Prologue: stage tile 0 fully (8 lines/wave outstanding).
  stageA(0, 0, 0); stageA(0, 0, 1); stageB(0, 0, 0); stageB(0, 0, 1);

  int cur = 0;
  bf16x8 af[4], bfr[4];
  for (int kt = 0; kt < KTILES; ++kt) {
    const bool pf = (kt + 1 < KTILES);
#pragma unroll
    for (int p = 0; p < 4; ++p) {
      const int ks = p >> 1, mh = p & 1;
      if (p == 0) {
        // Phase 0: stage next tile's A-h0, then confirm tile kt (vmcnt(2):
        // only the 2 just-issued loads may remain in flight).
        if (pf) {
          stageA(kt + 1, cur ^ 1, 0);
          asm volatile("s_waitcnt vmcnt(2)" ::: "memory");
        } else {
          asm volatile("s_waitcnt vmcnt(0)" ::: "memory");
        }
        __builtin_amdgcn_s_barrier();
        __builtin_amdgcn_sched_barrier(0);
        readB(bfr, cur, ks);
        readA(af, cur, ks, mh);
      } else {
        // Phases 1-3: data already confirmed -- issue ds_reads early so
        // their latency hides under the barrier wait.
        if (mh == 0) readB(bfr, cur, ks);
        readA(af, cur, ks, mh);
        if (pf) {
          if (p == 1) stageA(kt + 1, cur ^ 1, 1);
          else if (p == 2) stageB(kt + 1, cur ^ 1, 0);
          else stageB(kt + 1, cur ^ 1, 1);
        }
        __builtin_amdgcn_s_barrier();
        __builtin_amdgcn_sched_barrier(0);
      }
      __builtin_amdgcn_s_setprio(1);
#pragma unroll
      for (int m = 0; m < 4; ++m)
#pragma unroll
        for (int n = 0; n < 4; ++n)
          acc[mh * 4 + m][n] =
              __builtin_amdgcn_mfma_f32_16x16x32_bf16(af[m], bfr[n], acc[mh * 4 + m][n], 0, 0, 0);
      __builtin_amdgcn_s_setprio(0);
      __builtin_amdgcn_sched_barrier(0);
      __builtin_amdgcn_s_barrier();
    }
    cur ^= 1;
  }

  // C/D layout (m89-verified): col = lane&15, row = (lane>>4)*4 + j.
  const int ocol = colBase + wn * 64 + (lane & 15);
  const int orow = rowBase + wm * 128 + (lane >> 4) * 4;
#pragma unroll
  for (int m = 0; m < 8; ++m)
#pragma unroll
    for (int n = 0; n < 4; ++n)
#pragma unroll
      for (int j = 0; j < 4; ++j)
        qkv[(size_t)(orow + m * 16 + j) * N3 + ocol + n * 16] = acc[m][n][j];
}

// ---------------------------------------------------------------------------
// In-LDS 1024-pt complex radix-4 DIT FFT over the ZIDX-padded array.
DEV void fft1024_r4(float2* Z, const float2* tw, const int tid) {
#pragma unroll
  for (int s = 0; s < 5; ++s) {
    const int ls = 2 * s;
    const int L = 1 << ls;                     // 4^s
    const int i = tid & (L - 1);
    const int base = ((tid >> ls) << (ls + 2)) + i;   // g*4L + i
    const int tsh = 8 - ls;                    // twiddle step 256/L
    const float2 a = Z[ZIDX(base)];
    const float2 b = cmul(tw[i << tsh], Z[ZIDX(base + L)]);
    const float2 c = cmul(tw[(2 * i) << tsh], Z[ZIDX(base + 2 * L)]);
    const float2 d = cmul(tw[(3 * i) << tsh], Z[ZIDX(base + 3 * L)]);
    const float2 acp = cadd(a, c), acm = csub(a, c);
    const float2 bdp = cadd(b, d), bdm = csub(b, d);
    Z[ZIDX(base)]         = cadd(acp, bdp);                            // y0
    Z[ZIDX(base + L)]     = make_float2(acm.x + bdm.y, acm.y - bdm.x); // y1
    Z[ZIDX(base + 2 * L)] = csub(acp, bdp);                            // y2
    Z[ZIDX(base + 3 * L)] = make_float2(acm.x - bdm.y, acm.y + bdm.x); // y3
    __syncthreads();
  }
}

__global__ __launch_bounds__(256) void fwd_fft_k(float* __restrict__ qkv,
                                                 float2* __restrict__ fkv,   // [B][513][S]
                                                 const float2* __restrict__ gtw) {
  __shared__ float2 Z[ZLEN];
  __shared__ float2 tw[768];
  const int tid = threadIdx.x;
  const int bid = blockIdx.x;
  const int row = (bid & 7) * (BS / 8) + (bid >> 3);   // XCD-chunked swizzle
  const int b = row >> 11, s = row & 2047;
  init_tw(tw, gtw, tid);

  const float* kr = qkv + (size_t)row * N3 + DD;
  const float* vr = qkv + (size_t)row * N3 + 2 * DD;
  {
    const float4 k4 = reinterpret_cast<const float4*>(kr)[tid];
    const float4 v4 = reinterpret_cast<const float4*>(vr)[tid];
    const float kk[4] = {k4.x, k4.y, k4.z, k4.w};
    const float vv[4] = {v4.x, v4.y, v4.z, v4.w};
#pragma unroll
    for (int j = 0; j < 4; ++j) Z[ZIDX(rev4(tid * 4 + j))] = make_float2(kk[j], vv[j]);
  }
  __syncthreads();
  fft1024_r4(Z, tw, tid);
  // Z = FFT(k + i v): Fk = (Z[j]+conj(Z[N-j]))/2, Fv = -i(Z[j]-conj(Z[N-j]))/2
  for (int j = tid; j <= 512; j += 256) {
    const float2 Zj = Z[ZIDX(j)];
    const float2 Zc = conjf2(Z[ZIDX((1024 - j) & 1023)]);
    const float2 Fk = make_float2(0.5f * (Zj.x + Zc.x), 0.5f * (Zj.y + Zc.y));
    const float2 dv = csub(Zj, Zc);
    const float2 Fv = make_float2(0.5f * dv.y, -0.5f * dv.x);
    const float inv = 1.0f / (sqrtf(Fk.x * Fk.x + Fk.y * Fk.y) + 1e-8f);
    const float2 Fkh = make_float2(Fk.x * inv, Fk.y * inv);
    fkv[((size_t)b * NBIN + j) * SS + s] = cmul(Fkh, Fv);
  }
  __syncthreads();   // all reads of Z done before reuse

  // q FFT; Fqh written IN-PLACE over this row's own qkv storage (safe:
  // dataflow through LDS Z + barriers; row touched only by this block).
  const float* qr = qkv + (size_t)row * N3;
  {
    const float4 q4 = reinterpret_cast<const float4*>(qr)[tid];
    const float qq[4] = {q4.x, q4.y, q4.z, q4.w};
#pragma unroll
    for (int j = 0; j < 4; ++j) Z[ZIDX(rev4(tid * 4 + j))] = make_float2(qq[j], 0.0f);
  }
  __syncthreads();
  fft1024_r4(Z, tw, tid);
  float2* fqh_row = reinterpret_cast<float2*>(qkv + (size_t)row * N3);
  for (int j = tid; j <= 512; j += 256) {
    const float2 Fq = Z[ZIDX(j)];
    const float inv = 1.0f / (sqrtf(Fq.x * Fq.x + Fq.y * Fq.y) + 1e-8f);
    fqh_row[j] = make_float2(Fq.x * inv, Fq.y * inv);
  }
}

// ---------------------------------------------------------------------------
// Inclusive cumsum over S=2048 complex values; one block per (b,bin) chain.
__global__ __launch_bounds__(256) void scan_s_k(float2* __restrict__ fkv) {
  __shared__ float2 sums[256];
  const int tid = threadIdx.x;
  float2* p = fkv + (size_t)blockIdx.x * SS;
  float4* p4 = reinterpret_cast<float4*>(p);
  float4 d[4];
#pragma unroll
  for (int i = 0; i < 4; ++i) d[i] = p4[tid * 4 + i];
  float2* e = reinterpret_cast<float2*>(d);
#pragma unroll
  for (int i = 1; i < 8; ++i) e[i] = cadd(e[i], e[i - 1]);
  const float2 mytot = e[7];
  sums[tid] = mytot;
  float2 run = mytot;
  __syncthreads();
  for (int off = 1; off < 256; off <<= 1) {
    float2 addv = make_float2(0.0f, 0.0f);
    if (tid >= off) addv = sums[tid - off];
    __syncthreads();
    run = cadd(run, addv);
    sums[tid] = run;
    __syncthreads();
  }
  const float2 pre = csub(run, mytot);        // exclusive prefix of thread totals
#pragma unroll
  for (int i = 0; i < 8; ++i) e[i] = cadd(e[i], pre);
#pragma unroll
  for (int i = 0; i < 4; ++i) p4[tid * 4 + i] = d[i];
}

// ---------------------------------------------------------------------------
__global__ __launch_bounds__(256) void inv_fft_k(const float2* __restrict__ fkv,
                                                 const float* __restrict__ qkv,
                                                 float* __restrict__ out,
                                                 const float2* __restrict__ gtw) {
  __shared__ float2 Z[ZLEN];
  __shared__ float2 tw[768];
  const int tid = threadIdx.x;
  const int bid = blockIdx.x;
  const int row = (bid & 7) * (BS / 8) + (bid >> 3);   // XCD-chunked swizzle
  const int b = row >> 11, s = row & 2047;
  init_tw(tw, gtw, tid);

  // Y[j]=P[j] (j<=512), Y[1024-j]=conj(P[j]). FFT(conj(Y)) then Re()/N.
  const float2* fqh_row = reinterpret_cast<const float2*>(qkv + (size_t)row * N3);
  for (int j = tid; j <= 512; j += 256) {
    const float2 kv = fkv[((size_t)b * NBIN + j) * SS + s];
    const float2 qh = fqh_row[j];
    const float2 P = cmul(kv, conjf2(qh));
    Z[ZIDX(rev4(j))] = conjf2(P);
    if (j > 0 && j < 512) Z[ZIDX(rev4(1024 - j))] = P;
  }
  __syncthreads();
  fft1024_r4(Z, tw, tid);
  const float sc = 1.0f / 1024.0f;
  float4* o4 = reinterpret_cast<float4*>(out + (size_t)row * DD);
  o4[tid] = make_float4(Z[ZIDX(tid * 4 + 0)].x * sc, Z[ZIDX(tid * 4 + 1)].x * sc,
                        Z[ZIDX(tid * 4 + 2)].x * sc, Z[ZIDX(tid * 4 + 3)].x * sc);
}

// ---------------------------------------------------------------------------
extern "C" void kernel_launch(void* const* d_in, const int* in_sizes, int n_in,
                              void* d_out, int out_size, void* d_ws, size_t ws_size,
                              hipStream_t stream) {
  const float* x  = (const float*)d_in[0];
  const float* wq = (const float*)d_in[1];
  const float* wk = (const float*)d_in[2];
  const float* wv = (const float*)d_in[3];
  float* out = (float*)d_out;

  char* ws = (char*)d_ws;
  const size_t MB = 1024 * 1024;
  bf16*   xhi = (bf16*)(ws);                         // [0,16M)
  bf16*   xlo = (bf16*)(ws + 16 * MB);               // [16M,32M)
  float2* fkv = (float2*)(ws);                       // [0,32.07M) -- after GEMM
  float2* gtw = (float2*)(ws + 33 * MB);             // [33M,+6KB) twiddles
  bf16*   whi = (bf16*)(ws + 34 * MB);               // [34M,40M)
  bf16*   wlo = (bf16*)(ws + 40 * MB);               // [40M,46M)
  float*  qkv = (float*)(ws + 46 * MB);              // [46M,142M); rows carry Fqh later
  (void)ws_size; (void)in_sizes; (void)n_in; (void)out_size;

  tw_init_k<<<3, 256, 0, stream>>>(gtw);
  prep_x_k<<<BS * DD / 1024, 256, 0, stream>>>(x, xhi, xlo);
  prep_w_k<<<N3 * DD / 1024, 256, 0, stream>>>(wq, wk, wv, whi, wlo);
  gemm_8ph<<<(BS / 256) * (N3 / 256), 512, 0, stream>>>(xhi, xlo, whi, wlo, qkv);
  fwd_fft_k<<<BS, 256, 0, stream>>>(qkv, fkv, gtw);   // fkv overwrites xhi/xlo (dead)
  scan_s_k<<<BB * NBIN, 256, 0, stream>>>(fkv);
  inv_fft_k<<<BS, 256, 0, stream>>>(fkv, qkv, out, gtw);
}